// Round 1
// baseline (807.921 us; speedup 1.0000x reference)
//
#include <hip/hip_runtime.h>

// StepRelu: y = 0                       if x <= 0
//           y = (ceil(x/0.1)-1)*0.1     if 0 < x <= 1.6
//           y = x                       if x > 1.6
// Memory-bound elementwise over 2^27 fp32 elements (512 MiB in, 512 MiB out).
// float4 loads/stores (16 B/lane) for coalescing; plain fp32 division to
// match numpy's ceil(x/theta) bin edges exactly.

__device__ __forceinline__ float step_relu_1(float x) {
    const float theta = 0.1f;
    const float upper = theta * 16.0f;           // == 1.6000000238418579f
    float binned = (ceilf(x / theta) - 1.0f) * theta;
    float y = (x <= upper) ? binned : x;
    return (x <= 0.0f) ? 0.0f : y;
}

__global__ __launch_bounds__(256) void step_relu_kernel(
    const float4* __restrict__ in, float4* __restrict__ out, int n4) {
    int i = blockIdx.x * blockDim.x + threadIdx.x;
    if (i < n4) {
        float4 v = in[i];
        float4 r;
        r.x = step_relu_1(v.x);
        r.y = step_relu_1(v.y);
        r.z = step_relu_1(v.z);
        r.w = step_relu_1(v.w);
        out[i] = r;
    }
}

__global__ __launch_bounds__(256) void step_relu_tail(
    const float* __restrict__ in, float* __restrict__ out, int start, int n) {
    int i = start + blockIdx.x * blockDim.x + threadIdx.x;
    if (i < n) out[i] = step_relu_1(in[i]);
}

extern "C" void kernel_launch(void* const* d_in, const int* in_sizes, int n_in,
                              void* d_out, int out_size, void* d_ws, size_t ws_size,
                              hipStream_t stream) {
    const float* x = (const float*)d_in[0];
    float* y = (float*)d_out;
    int n = in_sizes[0];

    int n4 = n / 4;
    if (n4 > 0) {
        int blocks = (n4 + 255) / 256;
        step_relu_kernel<<<blocks, 256, 0, stream>>>(
            (const float4*)x, (float4*)y, n4);
    }
    int rem = n - n4 * 4;
    if (rem > 0) {
        step_relu_tail<<<1, 256, 0, stream>>>(x, y, n4 * 4, n);
    }
}

// Round 3
// 799.051 us; speedup vs baseline: 1.0111x; 1.0111x over previous
//
#include <hip/hip_runtime.h>

// StepRelu: y = 0                       if x <= 0
//           y = (ceil(x/0.1)-1)*0.1     if 0 < x <= 1.6
//           y = x                       if x > 1.6
// Memory-bound elementwise over 2^27 fp32 elements (512 MiB in, 512 MiB out).
// Native clang vector (ext_vector_type) so __builtin_nontemporal_* accepts
// the pointer; lowers to global_load/store_dwordx4 with nt bit — bypasses
// L2 write-allocate on this pure >L3-sized stream. Plain fp32 division kept
// to match numpy's ceil(x/theta) bin edges exactly (absmax 0.0 in R1).

typedef float vfloat4 __attribute__((ext_vector_type(4)));

__device__ __forceinline__ float step_relu_1(float x) {
    const float theta = 0.1f;
    const float upper = theta * 16.0f;           // == 1.6000000238418579f
    float binned = (ceilf(x / theta) - 1.0f) * theta;
    float y = (x <= upper) ? binned : x;
    return (x <= 0.0f) ? 0.0f : y;
}

__global__ __launch_bounds__(256) void step_relu_kernel(
    const vfloat4* __restrict__ in, vfloat4* __restrict__ out, int n4) {
    int i = blockIdx.x * blockDim.x + threadIdx.x;
    if (i < n4) {
        vfloat4 v = __builtin_nontemporal_load(&in[i]);
        vfloat4 r;
        r.x = step_relu_1(v.x);
        r.y = step_relu_1(v.y);
        r.z = step_relu_1(v.z);
        r.w = step_relu_1(v.w);
        __builtin_nontemporal_store(r, &out[i]);
    }
}

__global__ __launch_bounds__(256) void step_relu_tail(
    const float* __restrict__ in, float* __restrict__ out, int start, int n) {
    int i = start + blockIdx.x * blockDim.x + threadIdx.x;
    if (i < n) out[i] = step_relu_1(in[i]);
}

extern "C" void kernel_launch(void* const* d_in, const int* in_sizes, int n_in,
                              void* d_out, int out_size, void* d_ws, size_t ws_size,
                              hipStream_t stream) {
    const float* x = (const float*)d_in[0];
    float* y = (float*)d_out;
    int n = in_sizes[0];

    int n4 = n / 4;
    if (n4 > 0) {
        int blocks = (n4 + 255) / 256;
        step_relu_kernel<<<blocks, 256, 0, stream>>>(
            (const vfloat4*)x, (vfloat4*)y, n4);
    }
    int rem = n - n4 * 4;
    if (rem > 0) {
        step_relu_tail<<<1, 256, 0, stream>>>(x, y, n4 * 4, n);
    }
}